// Round 6
// baseline (358.256 us; speedup 1.0000x reference)
//
#include <hip/hip_runtime.h>

// BoundaryKDV7: per-pixel channel-softmax KL(T||S), masked by class-boundary
// pixels, binned per (batch, class 1..13), normalized, summed to scalar.
//
// Shapes: preds_S/preds_T [8,14,512,512] f32, gt [8,1,512,512] i32, out: 1 f32.
//
// R5: channel-major sweep + online softmax. R0-R4 post-mortem: five kernel
// structures (reg scalar/vector, hoisted, LDS-DMA burst, per-wave DMA
// pipeline) all plateau at 2.3-2.6 TB/s; R4 held ~10-20 MB in flight and
// replays served fully from IC are equally slow -> memory side is the
// saturated server; kernel-side MLP is not the lever. Remaining lever: run
// length per stream visit. Here each block owns 2048 px and sweeps c=0..13
// in channel-major order, reading each channel slice as an 8 KB contiguous
// run (was 256B-4KB), with per-pixel online-softmax stats (mS,zS,mT,zT,A)
// held in registers (8 px/thread = 40 stat VGPRs).

#define CC 14
#define KB 13          // boundary classes 1..13
#define BB 8
#define HH 512
#define WW 512
#define PP (HH * WW)   // 262144 pixels per image
#define PXT 8                       // px per thread (two float4 halves)
#define PXB (256 * PXT)             // 2048 px per block
#define BLOCKS_PER_IMG (PP / PXB)   // 128

// ws layout (floats): [0 .. 103] kl_sum[b][k-1], [104 .. 207] n[b][k-1]
#define NBINS (BB * KB)

__global__ void zero_ws_kernel(float* __restrict__ ws) {
    int i = threadIdx.x;
    if (i < 2 * NBINS) ws[i] = 0.0f;
}

__global__ __launch_bounds__(256, 3) void boundary_kl_kernel(
        const float* __restrict__ S, const float* __restrict__ T,
        const int* __restrict__ gt, float* __restrict__ ws) {
    const int tid = threadIdx.x;
    const int b   = blockIdx.x / BLOCKS_PER_IMG;
    const int p0  = (blockIdx.x % BLOCKS_PER_IMG) * PXB;   // multiple of 2048 (4 rows)

    __shared__ float s_kl[KB + 1];
    __shared__ float s_n[KB + 1];
    if (tid <= KB) { s_kl[tid] = 0.0f; s_n[tid] = 0.0f; }
    __syncthreads();

    const float* Sb = S + (size_t)b * CC * PP + p0;
    const float* Tb = T + (size_t)b * CC * PP + p0;
    const int*  gtb = gt + (size_t)b * PP;

    // two float4 columns per thread: half A at [0,1024), half B at [1024,2048)
    const int o0 = 4 * tid;
    const int o1 = 1024 + 4 * tid;

    // ---- boundary test first (its loads overlap the first channel loads) ----
    int contrib_mask = 0;   // bit i: pixel i contributes
    int kcls[PXT];
#pragma unroll
    for (int half = 0; half < 2; ++half) {
        const int pbase = p0 + (half ? o1 : o0);
        const int h = pbase >> 9;
        const int w = pbase & (WW - 1);
        int4 g  = *(const int4*)(gtb + pbase);
        int4 gu = make_int4(-1, -1, -1, -1);
        int4 gd = make_int4(-1, -1, -1, -1);
        if (h > 0)      gu = *(const int4*)(gtb + pbase - WW);
        if (h < HH - 1) gd = *(const int4*)(gtb + pbase + WW);
        const int gl = (w > 0)      ? gtb[pbase - 1] : -1;
        const int gr = (w + 4 < WW) ? gtb[pbase + 4] : -1;
        const int gc[4]  = {g.x, g.y, g.z, g.w};
        const int gup[4] = {gu.x, gu.y, gu.z, gu.w};
        const int gdn[4] = {gd.x, gd.y, gd.z, gd.w};
        const int glf[4] = {gl, g.x, g.y, g.z};
        const int grt[4] = {g.y, g.z, g.w, gr};
#pragma unroll
        for (int j = 0; j < 4; ++j) {
            const int i = half * 4 + j;
            const int k = gc[j];
            kcls[i] = k;
            const bool eroded = (glf[j] == k) & (grt[j] == k) & (gup[j] == k) & (gdn[j] == k);
            if (k >= 1 && !eroded) contrib_mask |= (1 << i);
        }
    }

    // ---- channel-major online-softmax sweep (8 KB contiguous run / slice) ----
    float mS[PXT], mT[PXT], zS[PXT], zT[PXT], A[PXT];
#pragma unroll
    for (int i = 0; i < PXT; ++i) {
        mS[i] = -1e30f; mT[i] = -1e30f;
        zS[i] = 0.f; zT[i] = 0.f; A[i] = 0.f;
    }

#pragma unroll
    for (int c = 0; c < CC; ++c) {
        const float* Sc = Sb + (size_t)c * PP;
        const float* Tc = Tb + (size_t)c * PP;
        const float4 sA = *(const float4*)(Sc + o0);
        const float4 sB = *(const float4*)(Sc + o1);
        const float4 tA = *(const float4*)(Tc + o0);
        const float4 tB = *(const float4*)(Tc + o1);
        const float xs[PXT] = {sA.x, sA.y, sA.z, sA.w, sB.x, sB.y, sB.z, sB.w};
        const float xt[PXT] = {tA.x, tA.y, tA.z, tA.w, tB.x, tB.y, tB.z, tB.w};
#pragma unroll
        for (int i = 0; i < PXT; ++i) {
            // online S: nmS >= mS and nmS >= xs, so both exps are <= 1
            const float nmS = fmaxf(mS[i], xs[i]);
            zS[i] = zS[i] * __expf(mS[i] - nmS) + __expf(xs[i] - nmS);
            mS[i] = nmS;
            // online T + cross term A = sum e^{xT-mT} (xT - xS)
            const float nmT = fmaxf(mT[i], xt[i]);
            const float sc = __expf(mT[i] - nmT);
            const float e  = __expf(xt[i] - nmT);
            zT[i] = zT[i] * sc + e;
            A[i]  = A[i]  * sc + e * (xt[i] - xs[i]);
            mT[i] = nmT;
        }
    }

    // ---- fold this thread's pixels into LDS bins ----
#pragma unroll
    for (int i = 0; i < PXT; ++i) {
        if (contrib_mask & (1 << i)) {
            const float kl = A[i] / zT[i] + (mS[i] + __logf(zS[i]))
                                         - (mT[i] + __logf(zT[i]));
            atomicAdd(&s_kl[kcls[i]], kl);
            atomicAdd(&s_n[kcls[i]], 1.0f);
        }
    }
    __syncthreads();

    if (tid >= 1 && tid <= KB) {
        atomicAdd(&ws[b * KB + (tid - 1)], s_kl[tid]);
        atomicAdd(&ws[NBINS + b * KB + (tid - 1)], s_n[tid]);
    }
}

__global__ void finalize_kernel(const float* __restrict__ ws,
                                const int* __restrict__ gt,
                                float* __restrict__ out) {
    __shared__ float partial[128];
    const int tid = threadIdx.x;  // 128 threads
    float t = 0.0f;
    if (tid < NBINS) {
        const int b = tid / KB;
        const int k = (tid % KB) + 1;
        const float kl = ws[tid];
        const float n  = ws[NBINS + tid];
        // Pixel p=0 of image b is a corner -> boundary iff gt[b,0,0] >= 1.
        // valid = exists boundary pixel with flat index > 0.
        const int k0 = gt[(size_t)b * PP];
        const float sub = (k0 == k) ? 1.0f : 0.0f;   // k >= 1 always here
        const float npos = n - sub;
        t = (npos > 0.0f) ? (kl / ((float)CC * fmaxf(n, 1.0f))) : 0.0f;
    }
    partial[tid] = t;
    __syncthreads();
    for (int s = 64; s > 0; s >>= 1) {
        if (tid < s) partial[tid] += partial[tid + s];
        __syncthreads();
    }
    if (tid == 0) out[0] = partial[0];  // LOSS_WEIGHT * TAU^2 = 1
}

extern "C" void kernel_launch(void* const* d_in, const int* in_sizes, int n_in,
                              void* d_out, int out_size, void* d_ws, size_t ws_size,
                              hipStream_t stream) {
    const float* S  = (const float*)d_in[0];
    const float* T  = (const float*)d_in[1];
    const int*   gt = (const int*)d_in[2];
    float* out = (float*)d_out;
    float* ws  = (float*)d_ws;

    hipLaunchKernelGGL(zero_ws_kernel, dim3(1), dim3(256), 0, stream, ws);
    hipLaunchKernelGGL(boundary_kl_kernel, dim3(BB * BLOCKS_PER_IMG), dim3(256), 0, stream,
                       S, T, gt, ws);
    hipLaunchKernelGGL(finalize_kernel, dim3(1), dim3(128), 0, stream, ws, gt, out);
}